// Round 13
// baseline (434.470 us; speedup 1.0000x reference)
//
#include <hip/hip_runtime.h>
#include <hip/hip_bf16.h>
#include <stdint.h>

#define VOCAB 17346050
#define EMB 2
#define SEQ 3335
#define BATCH 4096
#define BLOCK 256

// Native clang vector type — __builtin_nontemporal_load requires it.
typedef int int4v __attribute__((ext_vector_type(4)));

// One block per batch row. nvec = (SEQ - pro) >> 2 == 833 for all pro in 0..3.
// Each thread owns index chunks at tid, tid+256, tid+512, (tid+768 if <833):
// issue ALL index loads, then ALL 16 gathers, then consume — maximizes
// outstanding line-fetches per thread (MLP test vs. DRAM-random ceiling).
__global__ __launch_bounds__(BLOCK) void mlp_fused_kernel(
    const float* __restrict__ table,
    const float* __restrict__ conv_w,
    const float* __restrict__ dense_w,
    const int* __restrict__ idx,
    float* __restrict__ out)
{
    const int b = blockIdx.x;
    const int tid = threadIdx.x;
    const int* __restrict__ row = idx + (size_t)b * (size_t)SEQ;

    const int mis = (int)(((uintptr_t)row >> 2) & 3);
    const int pro = (4 - mis) & 3;          // 0..3
    const int nvec = (SEQ - pro) >> 2;      // always 833
    const int tail_start = pro + (nvec << 2);
    const int tail_cnt = SEQ - tail_start;  // 0..3

    float acc0 = 0.0f, acc1 = 0.0f;

    // Scalar prologue + tail (few elements, threads 0..2 at most).
    if (tid < pro) {
        const unsigned v = (unsigned)row[tid];
        const float2 e = *(const float2*)(table + (size_t)v * 2u);
        acc0 = fmaf(e.x, conv_w[tid], acc0);
        acc1 = fmaf(e.y, conv_w[SEQ + tid], acc1);
    }
    if (tid < tail_cnt) {
        const int l = tail_start + tid;
        const unsigned v = (unsigned)row[l];
        const float2 e = *(const float2*)(table + (size_t)v * 2u);
        acc0 = fmaf(e.x, conv_w[l], acc0);
        acc1 = fmaf(e.y, conv_w[SEQ + l], acc1);
    }

    const int4v* __restrict__ row4 = (const int4v*)(row + pro);

    // ---- Issue all 4 index loads ----
    const int j0 = tid;
    const int j1 = tid + 256;
    const int j2 = tid + 512;
    const bool m3 = (tid + 768) < nvec;     // tid < 65
    const int j3 = m3 ? (tid + 768) : 0;    // guarded: never OOB
    int4v v0 = __builtin_nontemporal_load(row4 + j0);
    int4v v1 = __builtin_nontemporal_load(row4 + j1);
    int4v v2 = __builtin_nontemporal_load(row4 + j2);
    int4v v3 = __builtin_nontemporal_load(row4 + j3);
    if (!m3) { v3.x = 0; v3.y = 0; v3.z = 0; v3.w = 0; }  // table[0] == 0 (padding row)

    // ---- Issue all 16 gathers back-to-back (16 outstanding per thread) ----
    const float2 e00 = *(const float2*)(table + (size_t)(unsigned)v0.x * 2u);
    const float2 e01 = *(const float2*)(table + (size_t)(unsigned)v0.y * 2u);
    const float2 e02 = *(const float2*)(table + (size_t)(unsigned)v0.z * 2u);
    const float2 e03 = *(const float2*)(table + (size_t)(unsigned)v0.w * 2u);
    const float2 e10 = *(const float2*)(table + (size_t)(unsigned)v1.x * 2u);
    const float2 e11 = *(const float2*)(table + (size_t)(unsigned)v1.y * 2u);
    const float2 e12 = *(const float2*)(table + (size_t)(unsigned)v1.z * 2u);
    const float2 e13 = *(const float2*)(table + (size_t)(unsigned)v1.w * 2u);
    const float2 e20 = *(const float2*)(table + (size_t)(unsigned)v2.x * 2u);
    const float2 e21 = *(const float2*)(table + (size_t)(unsigned)v2.y * 2u);
    const float2 e22 = *(const float2*)(table + (size_t)(unsigned)v2.z * 2u);
    const float2 e23 = *(const float2*)(table + (size_t)(unsigned)v2.w * 2u);
    const float2 e30 = *(const float2*)(table + (size_t)(unsigned)v3.x * 2u);
    const float2 e31 = *(const float2*)(table + (size_t)(unsigned)v3.y * 2u);
    const float2 e32 = *(const float2*)(table + (size_t)(unsigned)v3.z * 2u);
    const float2 e33 = *(const float2*)(table + (size_t)(unsigned)v3.w * 2u);

    // ---- Consume ----
    const int l0 = pro + (j0 << 2);
    const int l1 = pro + (j1 << 2);
    const int l2 = pro + (j2 << 2);
    const int l3 = m3 ? (pro + ((tid + 768) << 2)) : 0;  // clamped: weights finite, e3* == 0

    {
        const float* __restrict__ c = conv_w + l0;
        const float* __restrict__ d = conv_w + SEQ + l0;
        acc0 = fmaf(e00.x, c[0], acc0); acc1 = fmaf(e00.y, d[0], acc1);
        acc0 = fmaf(e01.x, c[1], acc0); acc1 = fmaf(e01.y, d[1], acc1);
        acc0 = fmaf(e02.x, c[2], acc0); acc1 = fmaf(e02.y, d[2], acc1);
        acc0 = fmaf(e03.x, c[3], acc0); acc1 = fmaf(e03.y, d[3], acc1);
    }
    {
        const float* __restrict__ c = conv_w + l1;
        const float* __restrict__ d = conv_w + SEQ + l1;
        acc0 = fmaf(e10.x, c[0], acc0); acc1 = fmaf(e10.y, d[0], acc1);
        acc0 = fmaf(e11.x, c[1], acc0); acc1 = fmaf(e11.y, d[1], acc1);
        acc0 = fmaf(e12.x, c[2], acc0); acc1 = fmaf(e12.y, d[2], acc1);
        acc0 = fmaf(e13.x, c[3], acc0); acc1 = fmaf(e13.y, d[3], acc1);
    }
    {
        const float* __restrict__ c = conv_w + l2;
        const float* __restrict__ d = conv_w + SEQ + l2;
        acc0 = fmaf(e20.x, c[0], acc0); acc1 = fmaf(e20.y, d[0], acc1);
        acc0 = fmaf(e21.x, c[1], acc0); acc1 = fmaf(e21.y, d[1], acc1);
        acc0 = fmaf(e22.x, c[2], acc0); acc1 = fmaf(e22.y, d[2], acc1);
        acc0 = fmaf(e23.x, c[3], acc0); acc1 = fmaf(e23.y, d[3], acc1);
    }
    {
        const float* __restrict__ c = conv_w + l3;
        const float* __restrict__ d = conv_w + SEQ + l3;
        acc0 = fmaf(e30.x, c[0], acc0); acc1 = fmaf(e30.y, d[0], acc1);
        acc0 = fmaf(e31.x, c[1], acc0); acc1 = fmaf(e31.y, d[1], acc1);
        acc0 = fmaf(e32.x, c[2], acc0); acc1 = fmaf(e32.y, d[2], acc1);
        acc0 = fmaf(e33.x, c[3], acc0); acc1 = fmaf(e33.y, d[3], acc1);
    }

    // Wave-level reduction (64 lanes).
    #pragma unroll
    for (int off = 32; off > 0; off >>= 1) {
        acc0 += __shfl_down(acc0, off, 64);
        acc1 += __shfl_down(acc1, off, 64);
    }

    __shared__ float s0[BLOCK / 64];
    __shared__ float s1[BLOCK / 64];
    const int wave = tid >> 6;
    const int lane = tid & 63;
    if (lane == 0) { s0[wave] = acc0; s1[wave] = acc1; }
    __syncthreads();

    if (tid == 0) {
        const float w0 = dense_w[0];
        const float w1 = dense_w[1];
        float x0 = s0[0] + s0[1] + s0[2] + s0[3];
        float x1 = s1[0] + s1[1] + s1[2] + s1[3];
        // hardswish: x * clip(x+3, 0, 6) / 6
        x0 = x0 * fminf(fmaxf(x0 + 3.0f, 0.0f), 6.0f) * (1.0f / 6.0f);
        x1 = x1 * fminf(fmaxf(x1 + 3.0f, 0.0f), 6.0f) * (1.0f / 6.0f);
        const float y = fmaf(x0, w0, x1 * w1);
        __builtin_nontemporal_store(tanhf(y), out + b);
    }
}

extern "C" void kernel_launch(void* const* d_in, const int* in_sizes, int n_in,
                              void* d_out, int out_size, void* d_ws, size_t ws_size,
                              hipStream_t stream) {
    const float* table   = (const float*)d_in[0];
    const float* conv_w  = (const float*)d_in[1];
    const float* dense_w = (const float*)d_in[2];
    const int*   idx     = (const int*)d_in[3];
    float*       out     = (float*)d_out;

    mlp_fused_kernel<<<BATCH, BLOCK, 0, stream>>>(table, conv_w, dense_w, idx, out);
}